// Round 2
// baseline (413.716 us; speedup 1.0000x reference)
//
#include <hip/hip_runtime.h>
#include <hip/hip_bf16.h>
#include <stdint.h>

// Problem constants (fixed by setup_inputs)
#define NTOK 8192
#define DMODEL 1280
#define NHEAD 16
#define HDIM 80
#define NSEG 16
#define SCALE_F 0.11180339887498949f
#define NEG_F -1e30f

typedef __bf16 bf16x8 __attribute__((ext_vector_type(8)));
typedef float f32x4 __attribute__((ext_vector_type(4)));

__device__ __forceinline__ void gload_lds16(const void* g, void* l) {
  __builtin_amdgcn_global_load_lds((__attribute__((address_space(1))) void*)g,
                                   (__attribute__((address_space(3))) void*)l,
                                   16, 0, 0);
}

// ---------------- fp32 -> bf16 convert (vectorized) ----------------
__global__ __launch_bounds__(256)
void cvt_f32_to_bf16(const float* __restrict__ src, __hip_bfloat16* __restrict__ dst) {
  int i = (blockIdx.x * 256 + threadIdx.x) * 4;
  float4 v = *(const float4*)(src + i);
  __align__(8) __hip_bfloat16 o[4] = {__float2bfloat16(v.x), __float2bfloat16(v.y),
                                      __float2bfloat16(v.z), __float2bfloat16(v.w)};
  *(uint2*)(dst + i) = *(const uint2*)o;
}

// ---------------- transpose fp32 (RxC) -> bf16 (CxR) ----------------
__global__ __launch_bounds__(256)
void transpose_w(const float* __restrict__ src, __hip_bfloat16* __restrict__ dst,
                 int R, int C) {
  __shared__ __hip_bfloat16 tile[32][33];
  int c0 = blockIdx.x * 32, r0 = blockIdx.y * 32;
  int tx = threadIdx.x & 31, ty = threadIdx.x >> 5;
#pragma unroll
  for (int i = 0; i < 4; ++i) {
    int r = ty + i * 8;
    tile[r][tx] = __float2bfloat16(src[(size_t)(r0 + r) * C + c0 + tx]);
  }
  __syncthreads();
#pragma unroll
  for (int i = 0; i < 4; ++i) {
    int r = ty + i * 8;
    dst[(size_t)(c0 + r) * R + r0 + tx] = tile[tx][r];
  }
}

// ---------------- RoPE in-place on q,k slices of qkv ----------------
__global__ __launch_bounds__(256)
void rope_inplace(__hip_bfloat16* __restrict__ qkv,
                  const float* __restrict__ cosb, const float* __restrict__ sinb) {
  int t = blockIdx.x * 256 + threadIdx.x;   // t < NTOK*NHEAD*40 exactly
  int dp = t % 40;
  int h = (t / 40) & 15;
  int n = t / 640;
  size_t base = (size_t)n * 3840 + h * 80;
  float c0 = cosb[n * 80 + dp], c1 = cosb[n * 80 + dp + 40];
  float s0 = sinb[n * 80 + dp], s1 = sinb[n * 80 + dp + 40];
  float q0 = __bfloat162float(qkv[base + dp]);
  float q1 = __bfloat162float(qkv[base + dp + 40]);
  qkv[base + dp]      = __float2bfloat16(q0 * c0 - q1 * s0);
  qkv[base + dp + 40] = __float2bfloat16(q1 * c1 + q0 * s1);
  float k0 = __bfloat162float(qkv[base + 1280 + dp]);
  float k1 = __bfloat162float(qkv[base + 1280 + dp + 40]);
  qkv[base + 1280 + dp]      = __float2bfloat16(k0 * c0 - k1 * s0);
  qkv[base + 1280 + dp + 40] = __float2bfloat16(k1 * c1 + k0 * s1);
}

// ---------------- 128x128 bf16 MFMA GEMM: C = A(MxK,lda) * Bt(NxK)^T + bias ----------------
// A_F32: A is fp32 in global, reg-staged + converted to bf16 LDS.
// else:  A is bf16, staged via global_load_lds (async DMA).
template <bool OUT_F32, bool A_F32>
__global__ __launch_bounds__(256)
void gemm128(const void* __restrict__ Av, int lda,
             const __hip_bfloat16* __restrict__ Bt,
             const float* __restrict__ bias,
             void* __restrict__ Cv, int M, int N, int K) {
  __shared__ __align__(16) __hip_bfloat16 lds[8192];  // A[128][32] @0, B[128][32] @4096
  const int tid = threadIdx.x;
  const int lane = tid & 63;
  const int wave = tid >> 6;
  const int wr = wave >> 1, wc = wave & 1;
  const int lr = lane & 15;
  const int lk = (lane >> 4) << 3;
  const int m0 = blockIdx.x * 128;
  const int n0 = blockIdx.y * 128;

  f32x4 zero = {0.f, 0.f, 0.f, 0.f};
  f32x4 acc[4][4];
#pragma unroll
  for (int i = 0; i < 4; ++i)
#pragma unroll
    for (int j = 0; j < 4; ++j) acc[i][j] = zero;

  for (int k0 = 0; k0 < K; k0 += 32) {
    // B staging via async DMA
#pragma unroll
    for (int j = 0; j < 2; ++j) {
      int v = j * 256 + tid;
      int row = v >> 2;
      int cb = (v & 3) << 3;
      gload_lds16(Bt + (size_t)(n0 + row) * K + k0 + cb,
                  &lds[4096 + wave * 512 + j * 2048]);
    }
    if constexpr (A_F32) {
      const float* A32 = (const float*)Av;
      float4 vv[4];
#pragma unroll
      for (int j = 0; j < 4; ++j) {
        int task = j * 256 + tid;
        int row = task >> 3, cc = task & 7;
        vv[j] = *(const float4*)(A32 + (size_t)(m0 + row) * lda + k0 + cc * 4);
      }
#pragma unroll
      for (int j = 0; j < 4; ++j) {
        int task = j * 256 + tid;
        int row = task >> 3, cc = task & 7;
        __align__(8) __hip_bfloat16 t[4] = {
            __float2bfloat16(vv[j].x), __float2bfloat16(vv[j].y),
            __float2bfloat16(vv[j].z), __float2bfloat16(vv[j].w)};
        *(uint2*)&lds[row * 32 + cc * 4] = *(const uint2*)t;
      }
    } else {
      const __hip_bfloat16* Abf = (const __hip_bfloat16*)Av;
#pragma unroll
      for (int j = 0; j < 2; ++j) {
        int v = j * 256 + tid;
        int row = v >> 2;
        int cb = (v & 3) << 3;
        gload_lds16(Abf + (size_t)(m0 + row) * lda + k0 + cb,
                    &lds[wave * 512 + j * 2048]);
      }
    }
    __syncthreads();

    bf16x8 af[4], bfr[4];
#pragma unroll
    for (int i = 0; i < 4; ++i) {
      af[i]  = *(const bf16x8*)&lds[(wr * 64 + i * 16 + lr) * 32 + lk];
      bfr[i] = *(const bf16x8*)&lds[4096 + (wc * 64 + i * 16 + lr) * 32 + lk];
    }
#pragma unroll
    for (int i = 0; i < 4; ++i)
#pragma unroll
      for (int j = 0; j < 4; ++j)
        acc[i][j] = __builtin_amdgcn_mfma_f32_16x16x32_bf16(af[i], bfr[j], acc[i][j], 0, 0, 0);
    __syncthreads();
  }

  const int r0 = (lane >> 4) << 2;
#pragma unroll
  for (int j = 0; j < 4; ++j) {
    int col = n0 + wc * 64 + j * 16 + lr;
    float bv = bias[col];
#pragma unroll
    for (int i = 0; i < 4; ++i) {
      int rowb = m0 + wr * 64 + i * 16 + r0;
#pragma unroll
      for (int r = 0; r < 4; ++r) {
        float val = acc[i][j][r] + bv;
        if (OUT_F32)
          ((float*)Cv)[(size_t)(rowb + r) * N + col] = val;
        else
          ((__hip_bfloat16*)Cv)[(size_t)(rowb + r) * N + col] = __float2bfloat16(val);
      }
    }
  }
}

// ---------------- varlen flash attention ----------------
// block = (qtile of 64 rows, head, seg); 4 waves x 16 q-rows.
// Reads Q/K/V from qkv; writes O back into the Q slice of qkv (each
// (token,head) Q-slice is read only by its own block, before its own write).
__global__ __launch_bounds__(256)
void attn_fwd(__hip_bfloat16* __restrict__ qkv, const int* __restrict__ cu) {
  const int qt = blockIdx.x, h = blockIdx.y, m = blockIdx.z;
  const int start = cu[m];
  const int L = cu[m + 1] - start;
  if (qt * 64 >= L) return;

  __shared__ __align__(16) __hip_bfloat16 Qs[64 * 104];
  __shared__ __align__(16) __hip_bfloat16 Ks[32 * 104];
  __shared__ __align__(16) __hip_bfloat16 Vs[80 * 40];   // [d][kv]
  __shared__ __align__(16) __hip_bfloat16 Ps[4][16 * 40];

  const int tid = threadIdx.x;
  const int lane = tid & 63;
  const int wave = tid >> 6;
  const int lr = lane & 15;
  const int lk = (lane >> 4) << 3;

  // stage Q tile (64 rows x 96 cols, cols 80..95 zero)
  for (int task = tid; task < 64 * 12; task += 256) {
    int r = task / 12, cc = task % 12;
    uint4 val = {0u, 0u, 0u, 0u};
    int qrow = qt * 64 + r;
    if (cc < 10 && qrow < L)
      val = *(const uint4*)(qkv + (size_t)(start + qrow) * 3840 + h * 80 + cc * 8);
    *(uint4*)&Qs[r * 104 + cc * 8] = val;
  }

  float m_run[4], l_run[4];
  f32x4 zero = {0.f, 0.f, 0.f, 0.f};
  f32x4 accO[5];
#pragma unroll
  for (int r = 0; r < 4; ++r) { m_run[r] = NEG_F; l_run[r] = 0.f; }
#pragma unroll
  for (int d = 0; d < 5; ++d) accO[d] = zero;

  for (int kt0 = 0; kt0 < L; kt0 += 32) {
    __syncthreads();  // prev compute done; Q staging visible after next barrier
    // stage K tile (32 x 96, zero-padded)
    for (int task = tid; task < 32 * 12; task += 256) {
      int r = task / 12, cc = task % 12;
      uint4 val = {0u, 0u, 0u, 0u};
      int krow = kt0 + r;
      if (cc < 10 && krow < L)
        val = *(const uint4*)(qkv + (size_t)(start + krow) * 3840 + 1280 + h * 80 + cc * 8);
      *(uint4*)&Ks[r * 104 + cc * 8] = val;
    }
    // stage V tile transposed in LDS: Vs[d][kv]
    for (int task = tid; task < 320; task += 256) {
      int r = task & 31, c = task >> 5;   // kv row, d-chunk
      uint4 val = {0u, 0u, 0u, 0u};
      int krow = kt0 + r;
      if (krow < L)
        val = *(const uint4*)(qkv + (size_t)(start + krow) * 3840 + 2560 + h * 80 + c * 8);
      __align__(16) __hip_bfloat16 t[8];
      *(uint4*)t = val;
#pragma unroll
      for (int e = 0; e < 8; ++e) Vs[(c * 8 + e) * 40 + r] = t[e];
    }
    __syncthreads();

    // QK^T : S (16 q-rows x 32 kv) per wave
    f32x4 s0 = zero, s1 = zero;
#pragma unroll
    for (int ks = 0; ks < 3; ++ks) {
      bf16x8 aq  = *(const bf16x8*)&Qs[(wave * 16 + lr) * 104 + ks * 32 + lk];
      bf16x8 bk0 = *(const bf16x8*)&Ks[lr * 104 + ks * 32 + lk];
      bf16x8 bk1 = *(const bf16x8*)&Ks[(16 + lr) * 104 + ks * 32 + lk];
      s0 = __builtin_amdgcn_mfma_f32_16x16x32_bf16(aq, bk0, s0, 0, 0, 0);
      s1 = __builtin_amdgcn_mfma_f32_16x16x32_bf16(aq, bk1, s1, 0, 0, 0);
    }
    const bool v0 = (kt0 + lr) < L;
    const bool v1 = (kt0 + 16 + lr) < L;
    float p0[4], p1[4], mx[4];
#pragma unroll
    for (int r = 0; r < 4; ++r) {
      float a = v0 ? s0[r] * SCALE_F : NEG_F;
      float b = v1 ? s1[r] * SCALE_F : NEG_F;
      p0[r] = a; p1[r] = b;
      mx[r] = fmaxf(a, b);
    }
#pragma unroll
    for (int off = 1; off < 16; off <<= 1)
#pragma unroll
      for (int r = 0; r < 4; ++r)
        mx[r] = fmaxf(mx[r], __shfl_xor(mx[r], off, 64));
    float rs[4];
#pragma unroll
    for (int r = 0; r < 4; ++r) {
      float mnew = fmaxf(m_run[r], mx[r]);
      float sf = __expf(m_run[r] - mnew);
      m_run[r] = mnew;
      p0[r] = __expf(p0[r] - mnew);
      p1[r] = __expf(p1[r] - mnew);
      rs[r] = p0[r] + p1[r];
      l_run[r] *= sf;
#pragma unroll
      for (int d = 0; d < 5; ++d) accO[d][r] *= sf;
    }
#pragma unroll
    for (int off = 1; off < 16; off <<= 1)
#pragma unroll
      for (int r = 0; r < 4; ++r)
        rs[r] += __shfl_xor(rs[r], off, 64);
#pragma unroll
    for (int r = 0; r < 4; ++r) l_run[r] += rs[r];

    // P -> per-wave LDS (bf16), then PV
#pragma unroll
    for (int r = 0; r < 4; ++r) {
      int prow = (lane >> 4) * 4 + r;
      Ps[wave][prow * 40 + lr]      = __float2bfloat16(p0[r]);
      Ps[wave][prow * 40 + 16 + lr] = __float2bfloat16(p1[r]);
    }
    bf16x8 ap = *(const bf16x8*)&Ps[wave][lr * 40 + lk];
#pragma unroll
    for (int d = 0; d < 5; ++d) {
      bf16x8 bv = *(const bf16x8*)&Vs[(d * 16 + lr) * 40 + lk];
      accO[d] = __builtin_amdgcn_mfma_f32_16x16x32_bf16(ap, bv, accO[d], 0, 0, 0);
    }
  }

  // epilogue: O / l -> back into Q slice of qkv
#pragma unroll
  for (int d = 0; d < 5; ++d) {
#pragma unroll
    for (int r = 0; r < 4; ++r) {
      int qrow = qt * 64 + wave * 16 + (lane >> 4) * 4 + r;
      if (qrow < L) {
        float o = accO[d][r] / l_run[r];
        qkv[(size_t)(start + qrow) * 3840 + h * 80 + d * 16 + lr] = __float2bfloat16(o);
      }
    }
  }
}

extern "C" void kernel_launch(void* const* d_in, const int* in_sizes, int n_in,
                              void* d_out, int out_size, void* d_ws, size_t ws_size,
                              hipStream_t stream) {
  const float* hidden = (const float*)d_in[0];
  const int*   cu     = (const int*)d_in[1];
  const float* cosb   = (const float*)d_in[2];
  const float* sinb   = (const float*)d_in[3];
  const float* Wqkv   = (const float*)d_in[4];
  const float* bqkv   = (const float*)d_in[5];
  const float* Wproj  = (const float*)d_in[6];
  const float* bproj  = (const float*)d_in[7];
  float* out = (float*)d_out;
  char* ws = (char*)d_ws;

  // workspace layout (bytes), required floor = 76,021,760
  __hip_bfloat16* qkv    = (__hip_bfloat16*)(ws);              // 8192x3840 bf16 (62.9MB)
  __hip_bfloat16* wqkvT  = (__hip_bfloat16*)(ws + 62914560);   // 3840x1280 (9.8MB)
  __hip_bfloat16* wprojT = (__hip_bfloat16*)(ws + 72744960);   // 1280x1280 (3.3MB)
  __hip_bfloat16* hbf    = (__hip_bfloat16*)(ws + 76021760);   // optional 8192x1280 (21MB)
  const bool use_hbf = ws_size >= (size_t)96993280;

  transpose_w<<<dim3(120, 40), 256, 0, stream>>>(Wqkv, wqkvT, 1280, 3840);
  transpose_w<<<dim3(40, 40), 256, 0, stream>>>(Wproj, wprojT, 1280, 1280);
  if (use_hbf) {
    cvt_f32_to_bf16<<<10240, 256, 0, stream>>>(hidden, hbf);
    gemm128<false, false><<<dim3(64, 30), 256, 0, stream>>>(hbf, 1280, wqkvT, bqkv, qkv, 8192, 3840, 1280);
  } else {
    gemm128<false, true><<<dim3(64, 30), 256, 0, stream>>>(hidden, 1280, wqkvT, bqkv, qkv, 8192, 3840, 1280);
  }
  rope_inplace<<<20480, 256, 0, stream>>>(qkv, cosb, sinb);
  attn_fwd<<<dim3(16, 16, 16), 256, 0, stream>>>(qkv, cu);
  gemm128<true, false><<<dim3(64, 10), 256, 0, stream>>>(qkv, 3840, wprojT, bproj, out, 8192, 1280, 1280);
}

// Round 3
// 413.709 us; speedup vs baseline: 1.0000x; 1.0000x over previous
//
#include <hip/hip_runtime.h>
#include <hip/hip_bf16.h>
#include <stdint.h>

// Problem constants (fixed by setup_inputs)
#define NTOK 8192
#define DMODEL 1280
#define NHEAD 16
#define HDIM 80
#define NSEG 16
#define SCALE_F 0.11180339887498949f
#define NEG_F -1e30f

typedef __bf16 bf16x8 __attribute__((ext_vector_type(8)));
typedef float f32x4 __attribute__((ext_vector_type(4)));

__device__ __forceinline__ void gload_lds16(const void* g, void* l) {
  __builtin_amdgcn_global_load_lds((__attribute__((address_space(1))) void*)g,
                                   (__attribute__((address_space(3))) void*)l,
                                   16, 0, 0);
}

// ---------------- fp32 -> bf16 convert (vectorized) ----------------
__global__ __launch_bounds__(256)
void cvt_f32_to_bf16(const float* __restrict__ src, __hip_bfloat16* __restrict__ dst) {
  int i = (blockIdx.x * 256 + threadIdx.x) * 4;
  float4 v = *(const float4*)(src + i);
  __align__(8) __hip_bfloat16 o[4] = {__float2bfloat16(v.x), __float2bfloat16(v.y),
                                      __float2bfloat16(v.z), __float2bfloat16(v.w)};
  *(uint2*)(dst + i) = *(const uint2*)o;
}

// ---------------- transpose fp32 (RxC) -> bf16 (CxR) ----------------
__global__ __launch_bounds__(256)
void transpose_w(const float* __restrict__ src, __hip_bfloat16* __restrict__ dst,
                 int R, int C) {
  __shared__ __hip_bfloat16 tile[32][33];
  int c0 = blockIdx.x * 32, r0 = blockIdx.y * 32;
  int tx = threadIdx.x & 31, ty = threadIdx.x >> 5;
#pragma unroll
  for (int i = 0; i < 4; ++i) {
    int r = ty + i * 8;
    tile[r][tx] = __float2bfloat16(src[(size_t)(r0 + r) * C + c0 + tx]);
  }
  __syncthreads();
#pragma unroll
  for (int i = 0; i < 4; ++i) {
    int r = ty + i * 8;
    dst[(size_t)(c0 + r) * R + r0 + tx] = tile[tx][r];
  }
}

// ---------------- RoPE in-place on q,k slices of qkv ----------------
__global__ __launch_bounds__(256)
void rope_inplace(__hip_bfloat16* __restrict__ qkv,
                  const float* __restrict__ cosb, const float* __restrict__ sinb) {
  int t = blockIdx.x * 256 + threadIdx.x;   // t < NTOK*NHEAD*40 exactly
  int dp = t % 40;
  int h = (t / 40) & 15;
  int n = t / 640;
  size_t base = (size_t)n * 3840 + h * 80;
  float c0 = cosb[n * 80 + dp], c1 = cosb[n * 80 + dp + 40];
  float s0 = sinb[n * 80 + dp], s1 = sinb[n * 80 + dp + 40];
  float q0 = __bfloat162float(qkv[base + dp]);
  float q1 = __bfloat162float(qkv[base + dp + 40]);
  qkv[base + dp]      = __float2bfloat16(q0 * c0 - q1 * s0);
  qkv[base + dp + 40] = __float2bfloat16(q1 * c1 + q0 * s1);
  float k0 = __bfloat162float(qkv[base + 1280 + dp]);
  float k1 = __bfloat162float(qkv[base + 1280 + dp + 40]);
  qkv[base + 1280 + dp]      = __float2bfloat16(k0 * c0 - k1 * s0);
  qkv[base + 1280 + dp + 40] = __float2bfloat16(k1 * c1 + k0 * s1);
}

// ---------------- 128x128 bf16 MFMA GEMM: C = A(MxK,lda) * Bt(NxK)^T + bias ----------------
// A_F32: A is fp32 in global, reg-staged + converted to bf16 LDS.
// else:  A is bf16, staged via global_load_lds (async DMA).
template <bool OUT_F32, bool A_F32>
__global__ __launch_bounds__(256)
void gemm128(const void* __restrict__ Av, int lda,
             const __hip_bfloat16* __restrict__ Bt,
             const float* __restrict__ bias,
             void* __restrict__ Cv, int M, int N, int K) {
  __shared__ __align__(16) __hip_bfloat16 lds[8192];  // A[128][32] @0, B[128][32] @4096
  const int tid = threadIdx.x;
  const int lane = tid & 63;
  const int wave = tid >> 6;
  const int wr = wave >> 1, wc = wave & 1;
  const int lr = lane & 15;
  const int lk = (lane >> 4) << 3;
  const int m0 = blockIdx.x * 128;
  const int n0 = blockIdx.y * 128;

  f32x4 zero = {0.f, 0.f, 0.f, 0.f};
  f32x4 acc[4][4];
#pragma unroll
  for (int i = 0; i < 4; ++i)
#pragma unroll
    for (int j = 0; j < 4; ++j) acc[i][j] = zero;

  for (int k0 = 0; k0 < K; k0 += 32) {
    // B staging via async DMA
#pragma unroll
    for (int j = 0; j < 2; ++j) {
      int v = j * 256 + tid;
      int row = v >> 2;
      int cb = (v & 3) << 3;
      gload_lds16(Bt + (size_t)(n0 + row) * K + k0 + cb,
                  &lds[4096 + wave * 512 + j * 2048]);
    }
    if constexpr (A_F32) {
      const float* A32 = (const float*)Av;
      float4 vv[4];
#pragma unroll
      for (int j = 0; j < 4; ++j) {
        int task = j * 256 + tid;
        int row = task >> 3, cc = task & 7;
        vv[j] = *(const float4*)(A32 + (size_t)(m0 + row) * lda + k0 + cc * 4);
      }
#pragma unroll
      for (int j = 0; j < 4; ++j) {
        int task = j * 256 + tid;
        int row = task >> 3, cc = task & 7;
        __align__(8) __hip_bfloat16 t[4] = {
            __float2bfloat16(vv[j].x), __float2bfloat16(vv[j].y),
            __float2bfloat16(vv[j].z), __float2bfloat16(vv[j].w)};
        *(uint2*)&lds[row * 32 + cc * 4] = *(const uint2*)t;
      }
    } else {
      const __hip_bfloat16* Abf = (const __hip_bfloat16*)Av;
#pragma unroll
      for (int j = 0; j < 2; ++j) {
        int v = j * 256 + tid;
        int row = v >> 2;
        int cb = (v & 3) << 3;
        gload_lds16(Abf + (size_t)(m0 + row) * lda + k0 + cb,
                    &lds[wave * 512 + j * 2048]);
      }
    }
    __syncthreads();

    bf16x8 af[4], bfr[4];
#pragma unroll
    for (int i = 0; i < 4; ++i) {
      af[i]  = *(const bf16x8*)&lds[(wr * 64 + i * 16 + lr) * 32 + lk];
      bfr[i] = *(const bf16x8*)&lds[4096 + (wc * 64 + i * 16 + lr) * 32 + lk];
    }
#pragma unroll
    for (int i = 0; i < 4; ++i)
#pragma unroll
      for (int j = 0; j < 4; ++j)
        acc[i][j] = __builtin_amdgcn_mfma_f32_16x16x32_bf16(af[i], bfr[j], acc[i][j], 0, 0, 0);
    __syncthreads();
  }

  const int r0 = (lane >> 4) << 2;
#pragma unroll
  for (int j = 0; j < 4; ++j) {
    int col = n0 + wc * 64 + j * 16 + lr;
    float bv = bias[col];
#pragma unroll
    for (int i = 0; i < 4; ++i) {
      int rowb = m0 + wr * 64 + i * 16 + r0;
#pragma unroll
      for (int r = 0; r < 4; ++r) {
        float val = acc[i][j][r] + bv;
        if (OUT_F32)
          ((float*)Cv)[(size_t)(rowb + r) * N + col] = val;
        else
          ((__hip_bfloat16*)Cv)[(size_t)(rowb + r) * N + col] = __float2bfloat16(val);
      }
    }
  }
}

// ---------------- varlen flash attention ----------------
// block = (qtile of 64 rows, head, seg); 4 waves x 16 q-rows.
// Reads Q/K/V from qkv; writes O back into the Q slice of qkv (each
// (token,head) Q-slice is read only by its own block, before its own write).
__global__ __launch_bounds__(256)
void attn_fwd(__hip_bfloat16* __restrict__ qkv, const int* __restrict__ cu) {
  const int qt = blockIdx.x, h = blockIdx.y, m = blockIdx.z;
  const int start = cu[m];
  const int L = cu[m + 1] - start;
  if (qt * 64 >= L) return;

  __shared__ __align__(16) __hip_bfloat16 Qs[64 * 104];
  __shared__ __align__(16) __hip_bfloat16 Ks[32 * 104];
  __shared__ __align__(16) __hip_bfloat16 Vs[80 * 40];   // [d][kv]
  __shared__ __align__(16) __hip_bfloat16 Ps[4][16 * 40];

  const int tid = threadIdx.x;
  const int lane = tid & 63;
  const int wave = tid >> 6;
  const int lr = lane & 15;
  const int lk = (lane >> 4) << 3;

  // stage Q tile (64 rows x 96 cols, cols 80..95 zero)
  for (int task = tid; task < 64 * 12; task += 256) {
    int r = task / 12, cc = task % 12;
    uint4 val = {0u, 0u, 0u, 0u};
    int qrow = qt * 64 + r;
    if (cc < 10 && qrow < L)
      val = *(const uint4*)(qkv + (size_t)(start + qrow) * 3840 + h * 80 + cc * 8);
    *(uint4*)&Qs[r * 104 + cc * 8] = val;
  }

  float m_run[4], l_run[4];
  f32x4 zero = {0.f, 0.f, 0.f, 0.f};
  f32x4 accO[5];
#pragma unroll
  for (int r = 0; r < 4; ++r) { m_run[r] = NEG_F; l_run[r] = 0.f; }
#pragma unroll
  for (int d = 0; d < 5; ++d) accO[d] = zero;

  for (int kt0 = 0; kt0 < L; kt0 += 32) {
    __syncthreads();  // prev compute done; Q staging visible after next barrier
    // stage K tile (32 x 96, zero-padded)
    for (int task = tid; task < 32 * 12; task += 256) {
      int r = task / 12, cc = task % 12;
      uint4 val = {0u, 0u, 0u, 0u};
      int krow = kt0 + r;
      if (cc < 10 && krow < L)
        val = *(const uint4*)(qkv + (size_t)(start + krow) * 3840 + 1280 + h * 80 + cc * 8);
      *(uint4*)&Ks[r * 104 + cc * 8] = val;
    }
    // stage V tile transposed in LDS: Vs[d][kv]
    for (int task = tid; task < 320; task += 256) {
      int r = task & 31, c = task >> 5;   // kv row, d-chunk
      uint4 val = {0u, 0u, 0u, 0u};
      int krow = kt0 + r;
      if (krow < L)
        val = *(const uint4*)(qkv + (size_t)(start + krow) * 3840 + 2560 + h * 80 + c * 8);
      __align__(16) __hip_bfloat16 t[8];
      *(uint4*)t = val;
#pragma unroll
      for (int e = 0; e < 8; ++e) Vs[(c * 8 + e) * 40 + r] = t[e];
    }
    __syncthreads();

    // QK^T : S (16 q-rows x 32 kv) per wave
    f32x4 s0 = zero, s1 = zero;
#pragma unroll
    for (int ks = 0; ks < 3; ++ks) {
      bf16x8 aq  = *(const bf16x8*)&Qs[(wave * 16 + lr) * 104 + ks * 32 + lk];
      bf16x8 bk0 = *(const bf16x8*)&Ks[lr * 104 + ks * 32 + lk];
      bf16x8 bk1 = *(const bf16x8*)&Ks[(16 + lr) * 104 + ks * 32 + lk];
      s0 = __builtin_amdgcn_mfma_f32_16x16x32_bf16(aq, bk0, s0, 0, 0, 0);
      s1 = __builtin_amdgcn_mfma_f32_16x16x32_bf16(aq, bk1, s1, 0, 0, 0);
    }
    const bool v0 = (kt0 + lr) < L;
    const bool v1 = (kt0 + 16 + lr) < L;
    float p0[4], p1[4], mx[4];
#pragma unroll
    for (int r = 0; r < 4; ++r) {
      float a = v0 ? s0[r] * SCALE_F : NEG_F;
      float b = v1 ? s1[r] * SCALE_F : NEG_F;
      p0[r] = a; p1[r] = b;
      mx[r] = fmaxf(a, b);
    }
#pragma unroll
    for (int off = 1; off < 16; off <<= 1)
#pragma unroll
      for (int r = 0; r < 4; ++r)
        mx[r] = fmaxf(mx[r], __shfl_xor(mx[r], off, 64));
    float rs[4];
#pragma unroll
    for (int r = 0; r < 4; ++r) {
      float mnew = fmaxf(m_run[r], mx[r]);
      float sf = __expf(m_run[r] - mnew);
      m_run[r] = mnew;
      p0[r] = __expf(p0[r] - mnew);
      p1[r] = __expf(p1[r] - mnew);
      rs[r] = p0[r] + p1[r];
      l_run[r] *= sf;
#pragma unroll
      for (int d = 0; d < 5; ++d) accO[d][r] *= sf;
    }
#pragma unroll
    for (int off = 1; off < 16; off <<= 1)
#pragma unroll
      for (int r = 0; r < 4; ++r)
        rs[r] += __shfl_xor(rs[r], off, 64);
#pragma unroll
    for (int r = 0; r < 4; ++r) l_run[r] += rs[r];

    // P -> per-wave LDS (bf16), then PV
#pragma unroll
    for (int r = 0; r < 4; ++r) {
      int prow = (lane >> 4) * 4 + r;
      Ps[wave][prow * 40 + lr]      = __float2bfloat16(p0[r]);
      Ps[wave][prow * 40 + 16 + lr] = __float2bfloat16(p1[r]);
    }
    bf16x8 ap = *(const bf16x8*)&Ps[wave][lr * 40 + lk];
#pragma unroll
    for (int d = 0; d < 5; ++d) {
      bf16x8 bv = *(const bf16x8*)&Vs[(d * 16 + lr) * 40 + lk];
      accO[d] = __builtin_amdgcn_mfma_f32_16x16x32_bf16(ap, bv, accO[d], 0, 0, 0);
    }
  }

  // epilogue: O / l -> back into Q slice of qkv
#pragma unroll
  for (int d = 0; d < 5; ++d) {
#pragma unroll
    for (int r = 0; r < 4; ++r) {
      int qrow = qt * 64 + wave * 16 + (lane >> 4) * 4 + r;
      if (qrow < L) {
        float o = accO[d][r] / l_run[r];
        qkv[(size_t)(start + qrow) * 3840 + h * 80 + d * 16 + lr] = __float2bfloat16(o);
      }
    }
  }
}

extern "C" void kernel_launch(void* const* d_in, const int* in_sizes, int n_in,
                              void* d_out, int out_size, void* d_ws, size_t ws_size,
                              hipStream_t stream) {
  const float* hidden = (const float*)d_in[0];
  const int*   cu     = (const int*)d_in[1];
  const float* cosb   = (const float*)d_in[2];
  const float* sinb   = (const float*)d_in[3];
  const float* Wqkv   = (const float*)d_in[4];
  const float* bqkv   = (const float*)d_in[5];
  const float* Wproj  = (const float*)d_in[6];
  const float* bproj  = (const float*)d_in[7];
  float* out = (float*)d_out;
  char* ws = (char*)d_ws;

  // workspace layout (bytes), required floor = 76,021,760
  __hip_bfloat16* qkv    = (__hip_bfloat16*)(ws);              // 8192x3840 bf16 (62.9MB)
  __hip_bfloat16* wqkvT  = (__hip_bfloat16*)(ws + 62914560);   // 3840x1280 (9.8MB)
  __hip_bfloat16* wprojT = (__hip_bfloat16*)(ws + 72744960);   // 1280x1280 (3.3MB)
  __hip_bfloat16* hbf    = (__hip_bfloat16*)(ws + 76021760);   // optional 8192x1280 (21MB)
  const bool use_hbf = ws_size >= (size_t)96993280;

  transpose_w<<<dim3(120, 40), 256, 0, stream>>>(Wqkv, wqkvT, 1280, 3840);
  transpose_w<<<dim3(40, 40), 256, 0, stream>>>(Wproj, wprojT, 1280, 1280);
  if (use_hbf) {
    cvt_f32_to_bf16<<<10240, 256, 0, stream>>>(hidden, hbf);
    gemm128<false, false><<<dim3(64, 30), 256, 0, stream>>>(hbf, 1280, wqkvT, bqkv, qkv, 8192, 3840, 1280);
  } else {
    gemm128<false, true><<<dim3(64, 30), 256, 0, stream>>>(hidden, 1280, wqkvT, bqkv, qkv, 8192, 3840, 1280);
  }
  rope_inplace<<<20480, 256, 0, stream>>>(qkv, cosb, sinb);
  attn_fwd<<<dim3(16, 16, 16), 256, 0, stream>>>(qkv, cu);
  gemm128<true, false><<<dim3(64, 10), 256, 0, stream>>>(qkv, 3840, wprojT, bproj, out, 8192, 1280, 1280);
}